// Round 1
// baseline (333.925 us; speedup 1.0000x reference)
//
#include <hip/hip_runtime.h>

// Problem constants
#define Bn     8
#define Cn     64
#define Hn     96
#define Wn     96
#define HW     9216        // Hn*Wn
#define K2     9
#define COUTn  64
#define KDIM   576         // Cn*K2
#define PTILE  128
#define NT     256
#define TILES_PER_IMG 72   // HW / PTILE
#define COLS_LD 132        // PTILE + 4 pad

__global__ __launch_bounds__(NT, 2)
void deform_conv_fp32(const float* __restrict__ x,
                      const float* __restrict__ offset,
                      const float* __restrict__ weight,
                      float* __restrict__ out) {
    __shared__ float  cols[64 * COLS_LD];     // 33.8 KB
    __shared__ int    sA[K2 * PTILE];         // 4.6 KB packed corner addr
    __shared__ float4 sW[K2 * PTILE];         // 18.4 KB bilinear weights

    const int tid  = threadIdx.x;
    const int blk  = blockIdx.x;
    const int b    = blk / TILES_PER_IMG;
    const int tile = blk - b * TILES_PER_IMG;
    const int pix0 = tile * PTILE;

    const float* xb   = x + (size_t)b * (Cn * HW);
    const float* offb = offset + (size_t)b * (2 * K2 * HW);

    // ---- Phase 0: per (k, p) sampling coordinates -> LDS ----
    for (int e = tid; e < K2 * PTILE; e += NT) {
        int k = e >> 7;              // e / PTILE
        int p = e & (PTILE - 1);
        int pix = pix0 + p;
        int h = pix / 96;
        int w = pix - h * 96;
        float offy = offb[(2 * k) * HW + pix];
        float offx = offb[(2 * k + 1) * HW + pix];
        float py = (float)(h - 1 + k / 3) + offy;
        float px = (float)(w - 1 + k % 3) + offx;
        float y0f = floorf(py), x0f = floorf(px);
        float ly = py - y0f, lx = px - x0f;
        int y0 = (int)y0f, x0 = (int)x0f;
        float vy0 = ((unsigned)y0 < 96u) ? 1.f : 0.f;
        float vy1 = ((unsigned)(y0 + 1) < 96u) ? 1.f : 0.f;
        float vx0 = ((unsigned)x0 < 96u) ? 1.f : 0.f;
        float vx1 = ((unsigned)(x0 + 1) < 96u) ? 1.f : 0.f;
        float w00 = (1.f - ly) * (1.f - lx) * vy0 * vx0;
        float w01 = (1.f - ly) * lx         * vy0 * vx1;
        float w10 = ly * (1.f - lx)         * vy1 * vx0;
        float w11 = ly * lx                 * vy1 * vx1;
        int y0c = min(max(y0, 0), 95);
        int x0c = min(max(x0, 0), 95);
        int y1c = min(max(y0 + 1, 0), 95);
        int x1c = min(max(x0 + 1, 0), 95);
        int dx = x1c - x0c;          // 0 or 1
        int dy = y1c - y0c;          // 0 or 1
        sA[e] = (y0c * 96 + x0c) | (dx << 14) | (dy << 15);
        sW[e] = make_float4(w00, w01, w10, w11);
    }

    float acc[8][4];
    #pragma unroll
    for (int oi = 0; oi < 8; ++oi)
        #pragma unroll
        for (int pi = 0; pi < 4; ++pi)
            acc[oi][pi] = 0.f;

    const int o0 = (tid >> 5) << 3;      // 0..56, 8 outputs per thread
    const int p0 = (tid & 31) << 2;      // 0..124, 4 pixels per thread

    for (int kc = 0; kc < K2; ++kc) {
        const int ckbase = kc * 64;
        __syncthreads();   // cols free to overwrite; phase0 data visible

        // ---- Sampling: 64 ck x 128 p -> cols ----
        #pragma unroll 4
        for (int i = 0; i < 32; ++i) {
            int s   = tid + i * NT;
            int p   = s & (PTILE - 1);
            int ckl = s >> 7;
            int ck  = ckbase + ckl;
            int c   = ck / 9;
            int k   = ck - c * 9;
            int pack  = sA[k * PTILE + p];
            float4 w4 = sW[k * PTILE + p];
            int a00  = pack & 16383;
            int dxv  = (pack >> 14) & 1;
            int dy96 = ((pack >> 15) & 1) * 96;
            const float* xc = xb + c * HW;
            float v = w4.x * xc[a00]
                    + w4.y * xc[a00 + dxv]
                    + w4.z * xc[a00 + dy96]
                    + w4.w * xc[a00 + dy96 + dxv];
            cols[ckl * COLS_LD + p] = v;
        }
        __syncthreads();

        // ---- GEMM accumulate: 8o x 4p per thread over 64 k-slices ----
        for (int j4 = 0; j4 < 64; j4 += 4) {
            float4 c0 = *(const float4*)&cols[(j4 + 0) * COLS_LD + p0];
            float4 c1 = *(const float4*)&cols[(j4 + 1) * COLS_LD + p0];
            float4 c2 = *(const float4*)&cols[(j4 + 2) * COLS_LD + p0];
            float4 c3 = *(const float4*)&cols[(j4 + 3) * COLS_LD + p0];
            #pragma unroll
            for (int oi = 0; oi < 8; ++oi) {
                float4 wv = *(const float4*)&weight[(o0 + oi) * KDIM + ckbase + j4];
                acc[oi][0] = fmaf(wv.x, c0.x, fmaf(wv.y, c1.x, fmaf(wv.z, c2.x, fmaf(wv.w, c3.x, acc[oi][0]))));
                acc[oi][1] = fmaf(wv.x, c0.y, fmaf(wv.y, c1.y, fmaf(wv.z, c2.y, fmaf(wv.w, c3.y, acc[oi][1]))));
                acc[oi][2] = fmaf(wv.x, c0.z, fmaf(wv.y, c1.z, fmaf(wv.z, c2.z, fmaf(wv.w, c3.z, acc[oi][2]))));
                acc[oi][3] = fmaf(wv.x, c0.w, fmaf(wv.y, c1.w, fmaf(wv.z, c2.w, fmaf(wv.w, c3.w, acc[oi][3]))));
            }
        }
    }

    // ---- Store ----
    #pragma unroll
    for (int oi = 0; oi < 8; ++oi) {
        float4 v = make_float4(acc[oi][0], acc[oi][1], acc[oi][2], acc[oi][3]);
        *(float4*)&out[(size_t)(b * COUTn + o0 + oi) * HW + pix0 + p0] = v;
    }
}

extern "C" void kernel_launch(void* const* d_in, const int* in_sizes, int n_in,
                              void* d_out, int out_size, void* d_ws, size_t ws_size,
                              hipStream_t stream) {
    const float* x      = (const float*)d_in[0];
    const float* offset = (const float*)d_in[1];
    const float* weight = (const float*)d_in[2];
    float* out = (float*)d_out;
    deform_conv_fp32<<<dim3(Bn * TILES_PER_IMG), dim3(NT), 0, stream>>>(x, offset, weight, out);
}

// Round 2
// 226.401 us; speedup vs baseline: 1.4749x; 1.4749x over previous
//
#include <hip/hip_runtime.h>

// Problem constants
#define Bn     8
#define Cn     64
#define Hn     96
#define Wn     96
#define HW     9216        // Hn*Wn
#define K2     9
#define COUTn  64
#define KDIM   576         // Cn*K2
#define BLK_PIX 64         // pixels per block (4 waves x 16)
#define BLKS_PER_IMG 144   // HW / BLK_PIX
#define NT     256

typedef __attribute__((ext_vector_type(8))) short  short8;   // 8 bf16 = 4 VGPR
typedef __attribute__((ext_vector_type(4))) float  float4v;  // MFMA acc

__device__ __forceinline__ short f2bf(float f) {
    unsigned u = __builtin_bit_cast(unsigned, f);
    u += 0x7FFFu + ((u >> 16) & 1u);          // RNE (inputs finite)
    return (short)(u >> 16);
}

__global__ void convert_weight(const float* __restrict__ w, short* __restrict__ wbf) {
    int i = blockIdx.x * 256 + threadIdx.x;
    if (i < COUTn * KDIM) wbf[i] = f2bf(w[i]);
}

__global__ __launch_bounds__(NT, 4)
void deform_conv_mfma(const float* __restrict__ x,
                      const float* __restrict__ offset,
                      const short* __restrict__ wbf,
                      float* __restrict__ out) {
    __shared__ int    sA[K2 * BLK_PIX];     // 2.25 KB packed corner addr
    __shared__ float4 sW[K2 * BLK_PIX];     // 9 KB bilinear weights

    const int tid  = threadIdx.x;
    const int b    = blockIdx.x / BLKS_PER_IMG;
    const int pix0 = (blockIdx.x - b * BLKS_PER_IMG) * BLK_PIX;

    const float* xb   = x + (size_t)b * (Cn * HW);
    const float* offb = offset + (size_t)b * (2 * K2 * HW);

    // ---- Phase 0: sampling metadata for (kk, pl) -> LDS, one barrier ----
    for (int e = tid; e < K2 * BLK_PIX; e += NT) {
        int kk = e >> 6;             // e / 64
        int pl = e & 63;
        int pix = pix0 + pl;
        int h = pix / 96, w = pix - h * 96;
        float offy = offb[(2 * kk) * HW + pix];
        float offx = offb[(2 * kk + 1) * HW + pix];
        float py = (float)(h - 1 + kk / 3) + offy;
        float px = (float)(w - 1 + kk % 3) + offx;
        float y0f = floorf(py), x0f = floorf(px);
        float ly = py - y0f, lx = px - x0f;
        int y0 = (int)y0f, x0 = (int)x0f;
        float vy0 = ((unsigned)y0 < 96u) ? 1.f : 0.f;
        float vy1 = ((unsigned)(y0 + 1) < 96u) ? 1.f : 0.f;
        float vx0 = ((unsigned)x0 < 96u) ? 1.f : 0.f;
        float vx1 = ((unsigned)(x0 + 1) < 96u) ? 1.f : 0.f;
        float w00 = (1.f - ly) * (1.f - lx) * vy0 * vx0;
        float w01 = (1.f - ly) * lx         * vy0 * vx1;
        float w10 = ly * (1.f - lx)         * vy1 * vx0;
        float w11 = ly * lx                 * vy1 * vx1;
        int y0c = min(max(y0, 0), 95);
        int x0c = min(max(x0, 0), 95);
        int dx = min(max(x0 + 1, 0), 95) - x0c;   // 0 or 1
        int dy = min(max(y0 + 1, 0), 95) - y0c;   // 0 or 1
        sA[e] = (y0c * 96 + x0c) | (dx << 14) | (dy << 15);
        sW[e] = make_float4(w00, w01, w10, w11);
    }
    __syncthreads();   // the only barrier

    const int lane = tid & 63;
    const int wv   = tid >> 6;
    const int q    = lane >> 4;          // quad 0..3
    const int r    = lane & 15;          // 0..15
    const int plw  = wv * 16 + r;        // this lane's B-column pixel (local)

    float4v acc0 = {0.f,0.f,0.f,0.f};
    float4v acc1 = {0.f,0.f,0.f,0.f};
    float4v acc2 = {0.f,0.f,0.f,0.f};
    float4v acc3 = {0.f,0.f,0.f,0.f};

    for (int ks = 0; ks < 18; ++ks) {
        const int kb = ks * 32;
        // A fragments: W[m = mt*16 + r][kb + q*8 .. +8], 16B aligned
        const short* wp = wbf + (size_t)r * KDIM + kb + q * 8;
        short8 a0 = *(const short8*)(wp + 0 * 16 * KDIM);
        short8 a1 = *(const short8*)(wp + 1 * 16 * KDIM);
        short8 a2 = *(const short8*)(wp + 2 * 16 * KDIM);
        short8 a3 = *(const short8*)(wp + 3 * 16 * KDIM);

        // B fragment: lane samples cols[k = kb + q*8 + j][pixel plw]
        short8 bq;
        #pragma unroll
        for (int j = 0; j < 8; ++j) {
            unsigned kg = (unsigned)(kb + q * 8 + j);
            unsigned c  = kg / 9u;
            unsigned kk = kg - c * 9u;
            int idx = (int)kk * BLK_PIX + plw;
            int pack  = sA[idx];
            float4 w4 = sW[idx];
            int a00  = pack & 16383;
            int dxv  = (pack >> 14) & 1;
            int dy96 = ((pack >> 15) & 1) * 96;
            const float* xc = xb + (size_t)c * HW;
            float v = w4.x * xc[a00]
                    + w4.y * xc[a00 + dxv]
                    + w4.z * xc[a00 + dy96]
                    + w4.w * xc[a00 + dy96 + dxv];
            bq[j] = f2bf(v);
        }

        acc0 = __builtin_amdgcn_mfma_f32_16x16x32_bf16(a0, bq, acc0, 0, 0, 0);
        acc1 = __builtin_amdgcn_mfma_f32_16x16x32_bf16(a1, bq, acc1, 0, 0, 0);
        acc2 = __builtin_amdgcn_mfma_f32_16x16x32_bf16(a2, bq, acc2, 0, 0, 0);
        acc3 = __builtin_amdgcn_mfma_f32_16x16x32_bf16(a3, bq, acc3, 0, 0, 0);
    }

    // ---- Store: D[row = cout = mt*16 + q*4 + reg][col = pixel] ----
    float* ob = out + (size_t)b * COUTn * HW + pix0 + plw;
    #pragma unroll
    for (int mt = 0; mt < 4; ++mt) {
        float4v a = (mt == 0) ? acc0 : (mt == 1) ? acc1 : (mt == 2) ? acc2 : acc3;
        float* p = ob + (size_t)(mt * 16 + q * 4) * HW;
        p[0 * HW] = a[0];
        p[1 * HW] = a[1];
        p[2 * HW] = a[2];
        p[3 * HW] = a[3];
    }
}

extern "C" void kernel_launch(void* const* d_in, const int* in_sizes, int n_in,
                              void* d_out, int out_size, void* d_ws, size_t ws_size,
                              hipStream_t stream) {
    const float* x      = (const float*)d_in[0];
    const float* offset = (const float*)d_in[1];
    const float* weight = (const float*)d_in[2];
    float* out = (float*)d_out;
    short* wbf = (short*)d_ws;   // 64*576*2 = 73728 B

    convert_weight<<<dim3((COUTn * KDIM + 255) / 256), dim3(256), 0, stream>>>(weight, wbf);
    deform_conv_mfma<<<dim3(Bn * BLKS_PER_IMG), dim3(NT), 0, stream>>>(x, offset, wbf, out);
}